// Round 7
// baseline (119.904 us; speedup 1.0000x reference)
//
#include <hip/hip_runtime.h>
#include <hip/hip_bf16.h>
#include <cstdint>

#define NHEADS 8
#define NPOINTS 4

typedef __bf16 bf16x8 __attribute__((ext_vector_type(8)));
typedef float f32x4 __attribute__((ext_vector_type(4)));

__device__ __forceinline__ ushort f2bf_rn(float x) {
  union { float f; uint32_t u; } c; c.f = x;
  uint32_t r = c.u + 0x7fffu + ((c.u >> 16) & 1u);
  return (ushort)(r >> 16);
}
__device__ __forceinline__ float bf2f(ushort h) {
  union { uint32_t u; float f; } c; c.u = ((uint32_t)h) << 16; return c.f;
}
__device__ __forceinline__ uint pack2(ushort a, ushort b) {
  return (uint)a | ((uint)b << 16);
}

// A-LDS rows are 128 B = 8 granules of 16 B: granules 0-3 = hi (32 bf16 of k),
// granules 4-7 = lo. Granule index XOR-swizzled by (row&7) (G4 pattern;
// conflict-free reads verified rounds 3-6).
__device__ __forceinline__ int gidx(int row, int g0) {
  return row * 64 + ((g0 ^ (row & 7)) << 3);
}

// Convert one thread's A chunk (fp32 -> hi/lo bf16) and store to LDS buffer.
template<int TM>
__device__ __forceinline__ void a_convert_store(
    ushort* Ab, int arow, int agq, float4 areg0, float4 areg1)
{
  if constexpr (TM == 64) {
    const float v[8] = {areg0.x, areg0.y, areg0.z, areg0.w,
                        areg1.x, areg1.y, areg1.z, areg1.w};
    ushort h[8], l[8];
#pragma unroll
    for (int j = 0; j < 8; ++j) {
      h[j] = f2bf_rn(v[j]);
      l[j] = f2bf_rn(v[j] - bf2f(h[j]));
    }
    uint4 hv = {pack2(h[0],h[1]), pack2(h[2],h[3]), pack2(h[4],h[5]), pack2(h[6],h[7])};
    uint4 lv = {pack2(l[0],l[1]), pack2(l[2],l[3]), pack2(l[4],l[5]), pack2(l[6],l[7])};
    *(uint4*)&Ab[gidx(arow, agq)]     = hv;
    *(uint4*)&Ab[gidx(arow, agq + 4)] = lv;
  } else {
    const float v[4] = {areg0.x, areg0.y, areg0.z, areg0.w};
    ushort h[4], l[4];
#pragma unroll
    for (int j = 0; j < 4; ++j) {
      h[j] = f2bf_rn(v[j]);
      l[j] = f2bf_rn(v[j] - bf2f(h[j]));
    }
    const int g = agq >> 1, half = (agq & 1) * 4;
    uint2 hv = {pack2(h[0],h[1]), pack2(h[2],h[3])};
    uint2 lv = {pack2(l[0],l[1]), pack2(l[2],l[3])};
    *(uint2*)&Ab[gidx(arow, g)     + half] = hv;
    *(uint2*)&Ab[gidx(arow, g + 4) + half] = lv;
  }
}

// ---------------------------------------------------------------------------
// Split-bf16 (3x MFMA) GEMM, N=256: C[M,256] = A[M,K] @ B[K,256] + bias.
// KEY STRUCTURE (round 7): B is NOT LDS-staged — it has zero intra-block
// reuse (each wave reads a disjoint 64-col slice exactly once). Bprep is
// laid out FRAGMENT-READY per (k-step, wave, nt, hi/lo): each lane's
// global_load_dwordx4 from the L2-resident 256 KB Bprep IS the MFMA
// fragment (1 KB/wave coalesced). No B barrier-drain at all.
// LDS holds only the A double buffer (2 x TM*128B) + epilogue tile:
// ~17 KB/block. One barrier per K-step (drains only cheap A ds_writes).
// A pipeline: reg-prefetch(t+1) -> MFMA(t) -> convert/ds_write(t+1) -> bar.
// ---------------------------------------------------------------------------
template<int TM>
__global__ __launch_bounds__(256, 3) void gemm_split3_n256(
    const float* __restrict__ A,
    const ushort* __restrict__ Bprep,   // [K/32][4 waves][8 frag][512] ushorts
    const float* __restrict__ bias, float* __restrict__ C,
    int M, int K)
{
  constexpr int MT = TM / 16;
  constexpr int AH = TM * 64;                    // ushorts per A buffer
  constexpr int CT = 16 * 260 * 2;               // epilogue tile ushorts
  constexpr int SM = (2 * AH > CT) ? 2 * AH : CT;
  __shared__ ushort smem[SM];
  const int tid  = threadIdx.x;
  const int lane = tid & 63, wave = tid >> 6;
  const int wn   = wave * 64;
  const int lrow = lane & 15, lgrp = lane >> 4;
  const long brow = (long)blockIdx.x * TM;
  const int NT = K >> 5;

  f32x4 acc[MT][4] = {};

  int arow, agq;
  if constexpr (TM == 64) { arow = tid >> 2; agq = tid & 3; }
  else                    { arow = tid >> 3; agq = tid & 7; }
  const float* Abase = &A[(size_t)(brow + arow) * K];

  float4 areg0 = {}, areg1 = {};

  // ---- prologue: stage A chunk 0 ----
  if constexpr (TM == 64) {
    areg0 = *(const float4*)(Abase + agq * 8);
    areg1 = *(const float4*)(Abase + agq * 8 + 4);
  } else {
    areg0 = *(const float4*)(Abase + agq * 4);
  }
  a_convert_store<TM>(smem, arow, agq, areg0, areg1);
  __syncthreads();

  ushort* Ac = smem;
  ushort* An = smem + AH;

  for (int t = 0; t < NT; ++t) {
    // ---- B fragments: direct coalesced dwordx4 from L2-resident Bprep ----
    const ushort* Bw = Bprep + (size_t)t * 16384 + wave * 4096 + lane * 8;
    uint4 braw[8];
#pragma unroll
    for (int f = 0; f < 8; ++f)
      braw[f] = *(const uint4*)(Bw + f * 512);

    const bool more = (t + 1 < NT);
    // ---- A(t+1) reg prefetch (flies under MFMA) ----
    if (more) {
      if constexpr (TM == 64) {
        areg0 = *(const float4*)(Abase + (t + 1) * 32 + agq * 8);
        areg1 = *(const float4*)(Abase + (t + 1) * 32 + agq * 8 + 4);
      } else {
        areg0 = *(const float4*)(Abase + (t + 1) * 32 + agq * 4);
      }
    }

    // ---- MFMA: A frags from LDS (streamed per mt), B frags from regs ----
#pragma unroll
    for (int mt = 0; mt < MT; ++mt) {
      const int r = mt * 16 + lrow;
      const bf16x8 ah = *(const bf16x8*)&Ac[gidx(r, lgrp)];
      const bf16x8 al = *(const bf16x8*)&Ac[gidx(r, lgrp + 4)];
#pragma unroll
      for (int nt = 0; nt < 4; ++nt) {
        const bf16x8 bh = *(const bf16x8*)&braw[nt * 2];
        const bf16x8 bl = *(const bf16x8*)&braw[nt * 2 + 1];
        acc[mt][nt] = __builtin_amdgcn_mfma_f32_16x16x32_bf16(ah, bh, acc[mt][nt], 0, 0, 0);
        acc[mt][nt] = __builtin_amdgcn_mfma_f32_16x16x32_bf16(ah, bl, acc[mt][nt], 0, 0, 0);
        acc[mt][nt] = __builtin_amdgcn_mfma_f32_16x16x32_bf16(al, bh, acc[mt][nt], 0, 0, 0);
      }
    }

    // ---- convert + ds_write A(t+1) into the other buffer ----
    if (more)
      a_convert_store<TM>(An, arow, agq, areg0, areg1);

    __syncthreads();   // seals An (lgkm only — no VMEM drain pressure)
    ushort* tmp = Ac; Ac = An; An = tmp;
  }

  // ---- epilogue: 16-row passes through LDS, full-line coalesced stores ----
  float bb[4];
#pragma unroll
  for (int nt = 0; nt < 4; ++nt) bb[nt] = bias[wn + nt * 16 + lrow];
  float* ctile = (float*)smem;               // 16 x 260 floats = 16.6 KB
#pragma unroll
  for (int h = 0; h < MT; ++h) {
    __syncthreads();
#pragma unroll
    for (int nt = 0; nt < 4; ++nt) {
      const int col = wn + nt * 16 + lrow;
#pragma unroll
      for (int j = 0; j < 4; ++j)
        ctile[(lgrp * 4 + j) * 260 + col] = acc[h][nt][j] + bb[nt];
    }
    __syncthreads();
#pragma unroll
    for (int i = 0; i < 4; ++i) {   // 16 rows * 64 float4 / 256 threads
      const int idx = i * 256 + tid, r = idx >> 6, c4 = (idx & 63) << 2;
      *(float4*)&C[(size_t)(brow + h * 16 + r) * 256 + c4] = *(const float4*)&ctile[r * 260 + c4];
    }
  }
}

// ---------------------------------------------------------------------------
// Weight prep: W fp32 [256][256] -> Bprep fragment-ready layout.
// Bprep ushort index = ((t*4 + w)*8 + nt*2 + h)*512 + lane*8 + j  where
// value = plane_h( W[k][col] ), k = t*32 + (lane>>4)*8 + j,
// col = w*64 + nt*16 + (lane&15).  Each 1 KB slab is one wave's dwordx4
// fragment load for (t, nt, hi/lo).
// ---------------------------------------------------------------------------
__global__ __launch_bounds__(256) void prep_wt(
    const float* __restrict__ W, ushort* __restrict__ Bprep)
{
  const int gid = blockIdx.x * 256 + threadIdx.x;  // 0..131071
  const int j    = gid & 7;
  const int lane = (gid >> 3) & 63;
  const int sub  = gid >> 9;          // t*32 + w*8 + nt*2 + h
  const int h  = sub & 1;
  const int nt = (sub >> 1) & 3;
  const int w  = (sub >> 3) & 3;
  const int t  = sub >> 5;
  const int k   = t * 32 + (lane >> 4) * 8 + j;
  const int col = w * 64 + nt * 16 + (lane & 15);
  const float v = W[(size_t)k * 256 + col];
  const ushort hi = f2bf_rn(v);
  Bprep[gid] = h ? f2bf_rn(v - bf2f(hi)) : hi;
}

// ---------------------------------------------------------------------------
// Offsets + attention-logits projection (unchanged).
// ---------------------------------------------------------------------------
__global__ __launch_bounds__(128) void proj_kernel(
    const float* __restrict__ query,
    const float* __restrict__ W_off, const float* __restrict__ b_off,
    const float* __restrict__ W_attn, const float* __restrict__ b_attn,
    float* __restrict__ offs, float* __restrict__ logits)
{
  __shared__ float q_lds[8][256];
  const int row0 = blockIdx.x * 8;
  const int tid  = threadIdx.x;

  for (int i = tid; i < 512; i += 128) {
    const int r  = i >> 6;
    const int c4 = (i & 63) << 2;
    *(float4*)&q_lds[r][c4] = *(const float4*)&query[(size_t)(row0 + r) * 256 + c4];
  }
  __syncthreads();
  if (tid >= 96) return;

  float acc[8] = {};
  if (tid < 64) {
    for (int k4 = 0; k4 < 256; k4 += 4) {
      const float w0 = W_off[(k4 + 0) * 64 + tid];
      const float w1 = W_off[(k4 + 1) * 64 + tid];
      const float w2 = W_off[(k4 + 2) * 64 + tid];
      const float w3 = W_off[(k4 + 3) * 64 + tid];
#pragma unroll
      for (int r = 0; r < 8; ++r) {
        float4 q4 = *(const float4*)&q_lds[r][k4];
        acc[r] += q4.x * w0 + q4.y * w1 + q4.z * w2 + q4.w * w3;
      }
    }
    const float bb = b_off[tid];
#pragma unroll
    for (int r = 0; r < 8; ++r)
      offs[(size_t)(row0 + r) * 64 + tid] = acc[r] + bb;
  } else {
    const int j = tid - 64;
    for (int k4 = 0; k4 < 256; k4 += 4) {
      const float w0 = W_attn[(k4 + 0) * 32 + j];
      const float w1 = W_attn[(k4 + 1) * 32 + j];
      const float w2 = W_attn[(k4 + 2) * 32 + j];
      const float w3 = W_attn[(k4 + 3) * 32 + j];
#pragma unroll
      for (int r = 0; r < 8; ++r) {
        float4 q4 = *(const float4*)&q_lds[r][k4];
        acc[r] += q4.x * w0 + q4.y * w1 + q4.z * w2 + q4.w * w3;
      }
    }
    const float bb = b_attn[j];
#pragma unroll
    for (int r = 0; r < 8; ++r)
      logits[(size_t)(row0 + r) * 32 + j] = acc[r] + bb;
  }
}

// ---------------------------------------------------------------------------
// Softmax + bilinear sampling, wave-per-query, float4 per lane (unchanged).
// ---------------------------------------------------------------------------
__global__ __launch_bounds__(256, 8) void sample_kernel(
    const float* __restrict__ refp,    // [BQ,2]
    const float* __restrict__ offs,    // [BQ,64]  (h*8 + p*2 + c)
    const float* __restrict__ logits,  // [BQ,32]  (h*4 + p)
    const float* __restrict__ values,  // [B,HW,256]
    float* __restrict__ mid,           // [BQ,256]
    const int* __restrict__ hptr, const int* __restrict__ wptr,
    int Q, int HW)
{
  const int lane = threadIdx.x & 63;
  const int bq   = blockIdx.x * 4 + (threadIdx.x >> 6);
  const int b    = bq / Q;
  const int W_   = *wptr;
  const int H_   = *hptr;
  const int h    = lane >> 3;

  const float l0 = logits[(size_t)bq * 32 + h * 4 + 0];
  const float l1 = logits[(size_t)bq * 32 + h * 4 + 1];
  const float l2 = logits[(size_t)bq * 32 + h * 4 + 2];
  const float l3 = logits[(size_t)bq * 32 + h * 4 + 3];
  const float m  = fmaxf(fmaxf(l0, l1), fmaxf(l2, l3));
  const float e0 = __expf(l0 - m), e1 = __expf(l1 - m);
  const float e2 = __expf(l2 - m), e3 = __expf(l3 - m);
  const float inv = 1.0f / (e0 + e1 + e2 + e3);
  float wt[4] = {e0 * inv, e1 * inv, e2 * inv, e3 * inv};

  const float rx = refp[(size_t)bq * 2 + 0];
  const float ry = refp[(size_t)bq * 2 + 1];
  const float* vb = values + (size_t)b * HW * 256;
  const int ch = lane * 4;

  f32x4 acc = {0.f, 0.f, 0.f, 0.f};
#pragma unroll
  for (int p = 0; p < NPOINTS; ++p) {
    float lx = rx + offs[(size_t)bq * 64 + h * 8 + p * 2 + 0];
    float ly = ry + offs[(size_t)bq * 64 + h * 8 + p * 2 + 1];
    lx = fminf(fmaxf(lx, 0.0f), 1.0f);
    ly = fminf(fmaxf(ly, 0.0f), 1.0f);
    const float sx = lx * (float)(W_ - 1);
    const float sy = ly * (float)(H_ - 1);
    int x0 = (int)floorf(sx);
    int y0 = (int)floorf(sy);
    x0 = min(max(x0, 0), W_ - 1);
    y0 = min(max(y0, 0), H_ - 1);
    const int x1 = min(x0 + 1, W_ - 1);
    const int y1 = min(y0 + 1, H_ - 1);
    const float wx1 = sx - (float)x0, wx0 = 1.0f - wx1;
    const float wy1 = sy - (float)y0, wy0 = 1.0f - wy1;

    const f32x4 g00 = *(const f32x4*)&vb[(size_t)(y0 * W_ + x0) * 256 + ch];
    const f32x4 g10 = *(const f32x4*)&vb[(size_t)(y0 * W_ + x1) * 256 + ch];
    const f32x4 g01 = *(const f32x4*)&vb[(size_t)(y1 * W_ + x0) * 256 + ch];
    const f32x4 g11 = *(const f32x4*)&vb[(size_t)(y1 * W_ + x1) * 256 + ch];

    const float w00 = wx0 * wy0, w10 = wx1 * wy0, w01 = wx0 * wy1, w11 = wx1 * wy1;
    const float wp = wt[p];
#pragma unroll
    for (int j = 0; j < 4; ++j)
      acc[j] += wp * (g00[j] * w00 + g01[j] * w01 + g10[j] * w10 + g11[j] * w11);
  }
  *(f32x4*)&mid[(size_t)bq * 256 + ch] = acc;
}

// ---------------------------------------------------------------------------
extern "C" void kernel_launch(void* const* d_in, const int* in_sizes, int n_in,
                              void* d_out, int out_size, void* d_ws, size_t ws_size,
                              hipStream_t stream)
{
  const float* query   = (const float*)d_in[0];
  const float* refp    = (const float*)d_in[1];
  const float* input_f = (const float*)d_in[2];
  const int*   hptr    = (const int*)d_in[3];
  const int*   wptr    = (const int*)d_in[4];
  const float* W_off   = (const float*)d_in[5];
  const float* b_off   = (const float*)d_in[6];
  const float* W_attn  = (const float*)d_in[7];
  const float* b_attn  = (const float*)d_in[8];
  const float* W_val   = (const float*)d_in[9];
  const float* b_val   = (const float*)d_in[10];
  const float* W_out   = (const float*)d_in[11];
  const float* b_out   = (const float*)d_in[12];
  float* out = (float*)d_out;

  const int D   = 256;
  const int BQ  = in_sizes[0] / D;   // 16384
  const int B   = 8;
  const int Q   = BQ / B;            // 2048
  const int BHW = in_sizes[2] / D;   // 80000
  const int HW  = BHW / B;           // 10000

  char* ws = (char*)d_ws;
  float* values = (float*)ws;                                   // 81.92 MB
  size_t o = (size_t)BHW * D * sizeof(float);
  float* offsb  = (float*)(ws + o);  o += (size_t)BQ * 64 * sizeof(float);  // 4.19 MB
  float* logitb = (float*)(ws + o);  o += (size_t)BQ * 32 * sizeof(float);  // 2.10 MB
  float* mid    = (float*)(ws + o);                             // 16.78 MB

  // Fragment-ready weight overlays on dead regions (256 KB each):
  //  - Bprep_val at head of `mid` (dead until sample writes mid)
  //  - Bprep_out at head of `offsb` (offs dead after sample; prep#2 runs after)
  ushort* Bprep_val = (ushort*)mid;
  ushort* Bprep_out = (ushort*)offsb;

  // 1. values = input_flatten @ W_val + b_val
  prep_wt<<<512, 256, 0, stream>>>(W_val, Bprep_val);
  gemm_split3_n256<64><<<BHW / 64, 256, 0, stream>>>(
      input_f, Bprep_val, b_val, values, BHW, D);

  // 2. offsets + attention logits
  proj_kernel<<<BQ / 8, 128, 0, stream>>>(
      query, W_off, b_off, W_attn, b_attn, offsb, logitb);

  // 3. softmax + bilinear sampling -> mid
  sample_kernel<<<BQ / 4, 256, 0, stream>>>(
      refp, offsb, logitb, values, mid, hptr, wptr, Q, HW);

  // 4. out = mid @ W_out + b_out
  prep_wt<<<512, 256, 0, stream>>>(W_out, Bprep_out);
  gemm_split3_n256<32><<<BQ / 32, 256, 0, stream>>>(
      mid, Bprep_out, b_out, out, BQ, D);
}

// Round 8
// 116.387 us; speedup vs baseline: 1.0302x; 1.0302x over previous
//
#include <hip/hip_runtime.h>
#include <hip/hip_bf16.h>
#include <cstdint>

#define NHEADS 8
#define NPOINTS 4

typedef __bf16 bf16x8 __attribute__((ext_vector_type(8)));
typedef float f32x4 __attribute__((ext_vector_type(4)));

__device__ __forceinline__ ushort f2bf_rn(float x) {
  union { float f; uint32_t u; } c; c.f = x;
  uint32_t r = c.u + 0x7fffu + ((c.u >> 16) & 1u);
  return (ushort)(r >> 16);
}
__device__ __forceinline__ float bf2f(ushort h) {
  union { uint32_t u; float f; } c; c.u = ((uint32_t)h) << 16; return c.f;
}
__device__ __forceinline__ uint pack2(ushort a, ushort b) {
  return (uint)a | ((uint)b << 16);
}

// A-LDS rows are 128 B = 8 granules of 16 B: granules 0-3 = hi (32 bf16 of k),
// granules 4-7 = lo. Granule index XOR-swizzled by (row&7) (G4 pattern;
// conflict-free reads verified rounds 3-7).
__device__ __forceinline__ int gidx(int row, int g0) {
  return row * 64 + ((g0 ^ (row & 7)) << 3);
}

// Convert one thread's A chunk (fp32 -> hi/lo bf16) and store to LDS buffer.
template<int TM>
__device__ __forceinline__ void a_convert_store(
    ushort* Ab, int arow, int agq, float4 areg0, float4 areg1)
{
  if constexpr (TM == 64) {
    const float v[8] = {areg0.x, areg0.y, areg0.z, areg0.w,
                        areg1.x, areg1.y, areg1.z, areg1.w};
    ushort h[8], l[8];
#pragma unroll
    for (int j = 0; j < 8; ++j) {
      h[j] = f2bf_rn(v[j]);
      l[j] = f2bf_rn(v[j] - bf2f(h[j]));
    }
    uint4 hv = {pack2(h[0],h[1]), pack2(h[2],h[3]), pack2(h[4],h[5]), pack2(h[6],h[7])};
    uint4 lv = {pack2(l[0],l[1]), pack2(l[2],l[3]), pack2(l[4],l[5]), pack2(l[6],l[7])};
    *(uint4*)&Ab[gidx(arow, agq)]     = hv;
    *(uint4*)&Ab[gidx(arow, agq + 4)] = lv;
  } else {
    const float v[4] = {areg0.x, areg0.y, areg0.z, areg0.w};
    ushort h[4], l[4];
#pragma unroll
    for (int j = 0; j < 4; ++j) {
      h[j] = f2bf_rn(v[j]);
      l[j] = f2bf_rn(v[j] - bf2f(h[j]));
    }
    const int g = agq >> 1, half = (agq & 1) * 4;
    uint2 hv = {pack2(h[0],h[1]), pack2(h[2],h[3])};
    uint2 lv = {pack2(l[0],l[1]), pack2(l[2],l[3])};
    *(uint2*)&Ab[gidx(arow, g)     + half] = hv;
    *(uint2*)&Ab[gidx(arow, g + 4) + half] = lv;
  }
}

// One pipelined K-step: issue B(t+1)->bnext + A(t+1)->regs, MFMA(t) on bcur,
// convert/ds_write A(t+1), barrier. bcur/bnext are distinct named arrays
// (static indexing — no scratch).
template<int TM, int MT>
__device__ __forceinline__ void gemm_step(
    const float* __restrict__ Abase, const ushort* __restrict__ Bprep,
    int t, int NT, const ushort* Ac, ushort* An,
    int arow, int agq, int lane, int wave, int lrow, int lgrp,
    const uint4 (&bcur)[8], uint4 (&bnext)[8], f32x4 (&acc)[MT][4])
{
  const bool more = (t + 1 < NT);

  // ---- issue B(t+1) fragment loads into the other reg buffer ----
  if (more) {
    const ushort* Bw = Bprep + (size_t)(t + 1) * 16384 + wave * 4096 + lane * 8;
#pragma unroll
    for (int f = 0; f < 8; ++f)
      bnext[f] = *(const uint4*)(Bw + f * 512);
  }

  // ---- issue A(t+1) reg prefetch ----
  float4 areg0 = {}, areg1 = {};
  if (more) {
    if constexpr (TM == 64) {
      areg0 = *(const float4*)(Abase + (t + 1) * 32 + agq * 8);
      areg1 = *(const float4*)(Abase + (t + 1) * 32 + agq * 8 + 4);
    } else {
      areg0 = *(const float4*)(Abase + (t + 1) * 32 + agq * 4);
    }
  }

  // ---- MFMA on bcur (loaded a full phase ago — latency covered) ----
#pragma unroll
  for (int mt = 0; mt < MT; ++mt) {
    const int r = mt * 16 + lrow;
    const bf16x8 ah = *(const bf16x8*)&Ac[gidx(r, lgrp)];
    const bf16x8 al = *(const bf16x8*)&Ac[gidx(r, lgrp + 4)];
#pragma unroll
    for (int nt = 0; nt < 4; ++nt) {
      const bf16x8 bh = *(const bf16x8*)&bcur[nt * 2];
      const bf16x8 bl = *(const bf16x8*)&bcur[nt * 2 + 1];
      acc[mt][nt] = __builtin_amdgcn_mfma_f32_16x16x32_bf16(ah, bh, acc[mt][nt], 0, 0, 0);
      acc[mt][nt] = __builtin_amdgcn_mfma_f32_16x16x32_bf16(ah, bl, acc[mt][nt], 0, 0, 0);
      acc[mt][nt] = __builtin_amdgcn_mfma_f32_16x16x32_bf16(al, bh, acc[mt][nt], 0, 0, 0);
    }
  }

  // ---- convert + ds_write A(t+1) (vmcnt wait on areg lands here) ----
  if (more)
    a_convert_store<TM>(An, arow, agq, areg0, areg1);

  __syncthreads();   // seals An (lgkm only — no VMEM drain pressure)
}

// ---------------------------------------------------------------------------
// Split-bf16 (3x MFMA) GEMM, N=256: C[M,256] = A[M,K] @ B[K,256] + bias.
// B is fragment-ready in Bprep (zero intra-block reuse -> no LDS for B);
// REGISTER-double-buffered: B(t+1) loads fly under MFMA(t) (this round's
// change — removes the ~200cy L2 wait from the top of every K-step).
// A: LDS double-buffer (2 x TM*128B), reg-prefetch -> MFMA -> convert.
// One barrier per K-step. NT = K/32 must be even.
// ---------------------------------------------------------------------------
template<int TM>
__global__ __launch_bounds__(256, 3) void gemm_split3_n256(
    const float* __restrict__ A,
    const ushort* __restrict__ Bprep,   // [K/32][4 waves][8 frag][512] ushorts
    const float* __restrict__ bias, float* __restrict__ C,
    int M, int K)
{
  constexpr int MT = TM / 16;
  constexpr int AH = TM * 64;                    // ushorts per A buffer
  constexpr int CT = 16 * 260 * 2;               // epilogue tile ushorts
  constexpr int SM = (2 * AH > CT) ? 2 * AH : CT;
  __shared__ ushort smem[SM];
  const int tid  = threadIdx.x;
  const int lane = tid & 63, wave = tid >> 6;
  const int wn   = wave * 64;
  const int lrow = lane & 15, lgrp = lane >> 4;
  const long brow = (long)blockIdx.x * TM;
  const int NT = K >> 5;

  f32x4 acc[MT][4] = {};
  uint4 brA[8], brB[8];

  int arow, agq;
  if constexpr (TM == 64) { arow = tid >> 2; agq = tid & 3; }
  else                    { arow = tid >> 3; agq = tid & 7; }
  const float* Abase = &A[(size_t)(brow + arow) * K];

  // ---- prologue: issue B(0)->brA, stage A(0) ----
  {
    const ushort* Bw0 = Bprep + wave * 4096 + lane * 8;
#pragma unroll
    for (int f = 0; f < 8; ++f)
      brA[f] = *(const uint4*)(Bw0 + f * 512);

    float4 areg0 = {}, areg1 = {};
    if constexpr (TM == 64) {
      areg0 = *(const float4*)(Abase + agq * 8);
      areg1 = *(const float4*)(Abase + agq * 8 + 4);
    } else {
      areg0 = *(const float4*)(Abase + agq * 4);
    }
    a_convert_store<TM>(smem, arow, agq, areg0, areg1);
  }
  __syncthreads();

  ushort* Ac = smem;
  ushort* An = smem + AH;

  for (int t = 0; t < NT; t += 2) {
    gemm_step<TM, MT>(Abase, Bprep, t,     NT, Ac, An, arow, agq,
                      lane, wave, lrow, lgrp, brA, brB, acc);
    { ushort* tmp = Ac; Ac = An; An = tmp; }
    gemm_step<TM, MT>(Abase, Bprep, t + 1, NT, Ac, An, arow, agq,
                      lane, wave, lrow, lgrp, brB, brA, acc);
    { ushort* tmp = Ac; Ac = An; An = tmp; }
  }

  // ---- epilogue: 16-row passes through LDS, full-line coalesced stores ----
  float bb[4];
#pragma unroll
  for (int nt = 0; nt < 4; ++nt) bb[nt] = bias[wn + nt * 16 + lrow];
  float* ctile = (float*)smem;               // 16 x 260 floats = 16.6 KB
#pragma unroll
  for (int h = 0; h < MT; ++h) {
    __syncthreads();
#pragma unroll
    for (int nt = 0; nt < 4; ++nt) {
      const int col = wn + nt * 16 + lrow;
#pragma unroll
      for (int j = 0; j < 4; ++j)
        ctile[(lgrp * 4 + j) * 260 + col] = acc[h][nt][j] + bb[nt];
    }
    __syncthreads();
#pragma unroll
    for (int i = 0; i < 4; ++i) {   // 16 rows * 64 float4 / 256 threads
      const int idx = i * 256 + tid, r = idx >> 6, c4 = (idx & 63) << 2;
      *(float4*)&C[(size_t)(brow + h * 16 + r) * 256 + c4] = *(const float4*)&ctile[r * 260 + c4];
    }
  }
}

// ---------------------------------------------------------------------------
// Weight prep: W fp32 [256][256] -> Bprep fragment-ready layout.
// Bprep ushort index = ((t*4 + w)*8 + nt*2 + h)*512 + lane*8 + j  where
// value = plane_h( W[k][col] ), k = t*32 + (lane>>4)*8 + j,
// col = w*64 + nt*16 + (lane&15).  Each 1 KB slab is one wave's dwordx4
// fragment load for (t, nt, hi/lo).
// ---------------------------------------------------------------------------
__global__ __launch_bounds__(256) void prep_wt(
    const float* __restrict__ W, ushort* __restrict__ Bprep)
{
  const int gid = blockIdx.x * 256 + threadIdx.x;  // 0..131071
  const int j    = gid & 7;
  const int lane = (gid >> 3) & 63;
  const int sub  = gid >> 9;          // t*32 + w*8 + nt*2 + h
  const int h  = sub & 1;
  const int nt = (sub >> 1) & 3;
  const int w  = (sub >> 3) & 3;
  const int t  = sub >> 5;
  const int k   = t * 32 + (lane >> 4) * 8 + j;
  const int col = w * 64 + nt * 16 + (lane & 15);
  const float v = W[(size_t)k * 256 + col];
  const ushort hi = f2bf_rn(v);
  Bprep[gid] = h ? f2bf_rn(v - bf2f(hi)) : hi;
}

// ---------------------------------------------------------------------------
// Offsets + attention-logits projection (unchanged).
// ---------------------------------------------------------------------------
__global__ __launch_bounds__(128) void proj_kernel(
    const float* __restrict__ query,
    const float* __restrict__ W_off, const float* __restrict__ b_off,
    const float* __restrict__ W_attn, const float* __restrict__ b_attn,
    float* __restrict__ offs, float* __restrict__ logits)
{
  __shared__ float q_lds[8][256];
  const int row0 = blockIdx.x * 8;
  const int tid  = threadIdx.x;

  for (int i = tid; i < 512; i += 128) {
    const int r  = i >> 6;
    const int c4 = (i & 63) << 2;
    *(float4*)&q_lds[r][c4] = *(const float4*)&query[(size_t)(row0 + r) * 256 + c4];
  }
  __syncthreads();
  if (tid >= 96) return;

  float acc[8] = {};
  if (tid < 64) {
    for (int k4 = 0; k4 < 256; k4 += 4) {
      const float w0 = W_off[(k4 + 0) * 64 + tid];
      const float w1 = W_off[(k4 + 1) * 64 + tid];
      const float w2 = W_off[(k4 + 2) * 64 + tid];
      const float w3 = W_off[(k4 + 3) * 64 + tid];
#pragma unroll
      for (int r = 0; r < 8; ++r) {
        float4 q4 = *(const float4*)&q_lds[r][k4];
        acc[r] += q4.x * w0 + q4.y * w1 + q4.z * w2 + q4.w * w3;
      }
    }
    const float bb = b_off[tid];
#pragma unroll
    for (int r = 0; r < 8; ++r)
      offs[(size_t)(row0 + r) * 64 + tid] = acc[r] + bb;
  } else {
    const int j = tid - 64;
    for (int k4 = 0; k4 < 256; k4 += 4) {
      const float w0 = W_attn[(k4 + 0) * 32 + j];
      const float w1 = W_attn[(k4 + 1) * 32 + j];
      const float w2 = W_attn[(k4 + 2) * 32 + j];
      const float w3 = W_attn[(k4 + 3) * 32 + j];
#pragma unroll
      for (int r = 0; r < 8; ++r) {
        float4 q4 = *(const float4*)&q_lds[r][k4];
        acc[r] += q4.x * w0 + q4.y * w1 + q4.z * w2 + q4.w * w3;
      }
    }
    const float bb = b_attn[j];
#pragma unroll
    for (int r = 0; r < 8; ++r)
      logits[(size_t)(row0 + r) * 32 + j] = acc[r] + bb;
  }
}

// ---------------------------------------------------------------------------
// Softmax + bilinear sampling, wave-per-query, float4 per lane (unchanged).
// ---------------------------------------------------------------------------
__global__ __launch_bounds__(256, 8) void sample_kernel(
    const float* __restrict__ refp,    // [BQ,2]
    const float* __restrict__ offs,    // [BQ,64]  (h*8 + p*2 + c)
    const float* __restrict__ logits,  // [BQ,32]  (h*4 + p)
    const float* __restrict__ values,  // [B,HW,256]
    float* __restrict__ mid,           // [BQ,256]
    const int* __restrict__ hptr, const int* __restrict__ wptr,
    int Q, int HW)
{
  const int lane = threadIdx.x & 63;
  const int bq   = blockIdx.x * 4 + (threadIdx.x >> 6);
  const int b    = bq / Q;
  const int W_   = *wptr;
  const int H_   = *hptr;
  const int h    = lane >> 3;

  const float l0 = logits[(size_t)bq * 32 + h * 4 + 0];
  const float l1 = logits[(size_t)bq * 32 + h * 4 + 1];
  const float l2 = logits[(size_t)bq * 32 + h * 4 + 2];
  const float l3 = logits[(size_t)bq * 32 + h * 4 + 3];
  const float m  = fmaxf(fmaxf(l0, l1), fmaxf(l2, l3));
  const float e0 = __expf(l0 - m), e1 = __expf(l1 - m);
  const float e2 = __expf(l2 - m), e3 = __expf(l3 - m);
  const float inv = 1.0f / (e0 + e1 + e2 + e3);
  float wt[4] = {e0 * inv, e1 * inv, e2 * inv, e3 * inv};

  const float rx = refp[(size_t)bq * 2 + 0];
  const float ry = refp[(size_t)bq * 2 + 1];
  const float* vb = values + (size_t)b * HW * 256;
  const int ch = lane * 4;

  f32x4 acc = {0.f, 0.f, 0.f, 0.f};
#pragma unroll
  for (int p = 0; p < NPOINTS; ++p) {
    float lx = rx + offs[(size_t)bq * 64 + h * 8 + p * 2 + 0];
    float ly = ry + offs[(size_t)bq * 64 + h * 8 + p * 2 + 1];
    lx = fminf(fmaxf(lx, 0.0f), 1.0f);
    ly = fminf(fmaxf(ly, 0.0f), 1.0f);
    const float sx = lx * (float)(W_ - 1);
    const float sy = ly * (float)(H_ - 1);
    int x0 = (int)floorf(sx);
    int y0 = (int)floorf(sy);
    x0 = min(max(x0, 0), W_ - 1);
    y0 = min(max(y0, 0), H_ - 1);
    const int x1 = min(x0 + 1, W_ - 1);
    const int y1 = min(y0 + 1, H_ - 1);
    const float wx1 = sx - (float)x0, wx0 = 1.0f - wx1;
    const float wy1 = sy - (float)y0, wy0 = 1.0f - wy1;

    const f32x4 g00 = *(const f32x4*)&vb[(size_t)(y0 * W_ + x0) * 256 + ch];
    const f32x4 g10 = *(const f32x4*)&vb[(size_t)(y0 * W_ + x1) * 256 + ch];
    const f32x4 g01 = *(const f32x4*)&vb[(size_t)(y1 * W_ + x0) * 256 + ch];
    const f32x4 g11 = *(const f32x4*)&vb[(size_t)(y1 * W_ + x1) * 256 + ch];

    const float w00 = wx0 * wy0, w10 = wx1 * wy0, w01 = wx0 * wy1, w11 = wx1 * wy1;
    const float wp = wt[p];
#pragma unroll
    for (int j = 0; j < 4; ++j)
      acc[j] += wp * (g00[j] * w00 + g01[j] * w01 + g10[j] * w10 + g11[j] * w11);
  }
  *(f32x4*)&mid[(size_t)bq * 256 + ch] = acc;
}

// ---------------------------------------------------------------------------
extern "C" void kernel_launch(void* const* d_in, const int* in_sizes, int n_in,
                              void* d_out, int out_size, void* d_ws, size_t ws_size,
                              hipStream_t stream)
{
  const float* query   = (const float*)d_in[0];
  const float* refp    = (const float*)d_in[1];
  const float* input_f = (const float*)d_in[2];
  const int*   hptr    = (const int*)d_in[3];
  const int*   wptr    = (const int*)d_in[4];
  const float* W_off   = (const float*)d_in[5];
  const float* b_off   = (const float*)d_in[6];
  const float* W_attn  = (const float*)d_in[7];
  const float* b_attn  = (const float*)d_in[8];
  const float* W_val   = (const float*)d_in[9];
  const float* b_val   = (const float*)d_in[10];
  const float* W_out   = (const float*)d_in[11];
  const float* b_out   = (const float*)d_in[12];
  float* out = (float*)d_out;

  const int D   = 256;
  const int BQ  = in_sizes[0] / D;   // 16384
  const int B   = 8;
  const int Q   = BQ / B;            // 2048
  const int BHW = in_sizes[2] / D;   // 80000
  const int HW  = BHW / B;           // 10000

  char* ws = (char*)d_ws;
  float* values = (float*)ws;                                   // 81.92 MB
  size_t o = (size_t)BHW * D * sizeof(float);
  float* offsb  = (float*)(ws + o);  o += (size_t)BQ * 64 * sizeof(float);  // 4.19 MB
  float* logitb = (float*)(ws + o);  o += (size_t)BQ * 32 * sizeof(float);  // 2.10 MB
  float* mid    = (float*)(ws + o);                             // 16.78 MB

  // Fragment-ready weight overlays on dead regions (256 KB each):
  //  - Bprep_val at head of `mid` (dead until sample writes mid)
  //  - Bprep_out at head of `offsb` (offs dead after sample; prep#2 runs after)
  ushort* Bprep_val = (ushort*)mid;
  ushort* Bprep_out = (ushort*)offsb;

  // 1. values = input_flatten @ W_val + b_val
  prep_wt<<<512, 256, 0, stream>>>(W_val, Bprep_val);
  gemm_split3_n256<64><<<BHW / 64, 256, 0, stream>>>(
      input_f, Bprep_val, b_val, values, BHW, D);

  // 2. offsets + attention logits
  proj_kernel<<<BQ / 8, 128, 0, stream>>>(
      query, W_off, b_off, W_attn, b_attn, offsb, logitb);

  // 3. softmax + bilinear sampling -> mid
  sample_kernel<<<BQ / 4, 256, 0, stream>>>(
      refp, offsb, logitb, values, mid, hptr, wptr, Q, HW);

  // 4. out = mid @ W_out + b_out
  prep_wt<<<512, 256, 0, stream>>>(W_out, Bprep_out);
  gemm_split3_n256<32><<<BQ / 32, 256, 0, stream>>>(
      mid, Bprep_out, b_out, out, BQ, D);
}